// Round 2
// baseline (290.569 us; speedup 1.0000x reference)
//
#include <hip/hip_runtime.h>
#include <math.h>

#define Bsz 64
#define Tn 200
#define NUMC 2000
#define DS 128
#define SM 50
#define NTOK (Bsz*Tn)
#define WVS 10       // waves per fused block
#define MPG 10       // m per scan wave (5 m-groups x 2 d-halves = 10 waves)

typedef __attribute__((ext_vector_type(8))) short bfrag;
typedef __attribute__((ext_vector_type(4))) float f32x4;
typedef __attribute__((ext_vector_type(4))) unsigned int u32x4;

__device__ __forceinline__ unsigned short f2bf(float x) {
    unsigned int u = __builtin_bit_cast(unsigned int, x);
    u = u + 0x7fffu + ((u >> 16) & 1u);   // RNE
    return (unsigned short)(u >> 16);
}
__device__ __forceinline__ unsigned int pack2(float a, float b) {
    return (unsigned int)f2bf(a) | ((unsigned int)f2bf(b) << 16);
}
__device__ __forceinline__ bfrag mk_frag(f32x4 x, f32x4 y) {
    u32x4 t;
    t[0] = pack2(x[0], x[1]); t[1] = pack2(x[2], x[3]);
    t[2] = pack2(y[0], y[1]); t[3] = pack2(y[2], y[3]);
    return __builtin_bit_cast(bfrag, t);
}

// fast transcendentals: v_exp_f32 / v_rcp_f32 (~1e-6 rel err, invisible at bf16 grade)
__device__ __forceinline__ float fast_exp(float x)  { return __builtin_amdgcn_exp2f(x * 1.44269504f); }
__device__ __forceinline__ float fast_rcp(float x)  { return __builtin_amdgcn_rcpf(x); }
__device__ __forceinline__ float fast_sigmoid(float x) { return fast_rcp(1.f + fast_exp(-x)); }
__device__ __forceinline__ float fast_tanh(float x) { return 1.f - 2.f * fast_rcp(fast_exp(2.f * x) + 1.f); }

__device__ __forceinline__ void load_group(const bfrag* __restrict__ B, int nt0, int L, bfrag bf[4][4]) {
    #pragma unroll
    for (int t = 0; t < 4; t++)
        #pragma unroll
        for (int ki = 0; ki < 4; ki++)
            bf[t][ki] = B[(size_t)((nt0 + t) * 4 + ki) * 64 + L];
}
__device__ __forceinline__ void mfma_group(const bfrag A[4], const bfrag bf[4][4], f32x4 acc[4]) {
    #pragma unroll
    for (int ki = 0; ki < 4; ki++)
        #pragma unroll
        for (int t = 0; t < 4; t++)
            acc[t] = __builtin_amdgcn_mfma_f32_16x16x32_bf16(A[ki], bf[t][ki], acc[t], 0, 0, 0);
}

// ---------------- K0: cast weights into MFMA b-frag block layout ----------------
// lane L holds W[n = nt*16 + (L&15)][k = ki*32 + (L>>4)*8 + j], j=0..7.
// Bea: rows 0-127 = e_W, 128-255 = a_W          (16 n-tiles)
// Bkm: rows 0-127 = f_W[:,128:256], 128-177 = Mk, 178-191 = 0   (12 n-tiles)
// Bf0: rows 0-127 = f_W[:,0:128]                (8 n-tiles)
__global__ __launch_bounds__(256) void k0_cast(
    const float* __restrict__ eW, const float* __restrict__ aW,
    const float* __restrict__ fW, const float* __restrict__ Mk,
    unsigned int* __restrict__ BeaU, unsigned int* __restrict__ BkmU,
    unsigned int* __restrict__ Bf0U)
{
    const int g = blockIdx.x * 256 + threadIdx.x;
    if (g >= 9216) return;
    int gm, mat;
    unsigned int* dst;
    if (g < 4096)      { mat = 0; gm = g;        dst = BeaU; }
    else if (g < 7168) { mat = 1; gm = g - 4096; dst = BkmU; }
    else               { mat = 2; gm = g - 7168; dst = Bf0U; }
    const int nt = gm >> 8, r = gm & 255, ki = r >> 6, L = r & 63;
    const int n = nt * 16 + (L & 15);
    const int k = ki * 32 + (L >> 4) * 8;

    const float* src = nullptr;
    if (mat == 0) {
        src = (n < 128) ? (eW + (size_t)n * DS + k) : (aW + (size_t)(n - 128) * DS + k);
    } else if (mat == 1) {
        if (n < 128)      src = fW + (size_t)n * (2 * DS) + DS + k;
        else if (n < 128 + SM) src = Mk + (size_t)(n - 128) * DS + k;
    } else {
        src = fW + (size_t)n * (2 * DS) + k;
    }
    float v[8];
    #pragma unroll
    for (int j = 0; j < 8; j++) v[j] = src ? src[j] : 0.f;
    u32x4 o;
    o[0] = pack2(v[0], v[1]); o[1] = pack2(v[2], v[3]);
    o[2] = pack2(v[4], v[5]); o[3] = pack2(v[6], v[7]);
    ((u32x4*)dst)[gm] = o;
}

// ---------------- KF: fused gemm + scan + f-gemm + pred. One block per batch row. ----------------
// Phase A: 13 token-tiles over 10 waves: e,a (sigmoid/tanh), kp, w (wave-parallel softmax) -> global
// Phase B: scan; wave wv = (dh = wv/5, mg = wv%5), MPG=10; cross-wave reduce -> reads in LDS (bf16)
// Phase D: f-GEMM from LDS reads + kp + bias -> tanh -> pred gather-dot -> out
__global__ __launch_bounds__(640) void kf_fused(
    const int* __restrict__ skill, const int* __restrict__ answer,
    const float* __restrict__ k_emb, const float* __restrict__ v_emb,
    const unsigned int* __restrict__ BeaU, const unsigned int* __restrict__ BkmU,
    const unsigned int* __restrict__ Bf0U,
    const float* __restrict__ eB, const float* __restrict__ aB,
    const float* __restrict__ Mv0, const float* __restrict__ fB,
    const float* __restrict__ pW, const float* __restrict__ pB,
    float* __restrict__ e_buf, float* __restrict__ a_buf,
    float* __restrict__ w_buf, float* __restrict__ kp_buf,
    float* __restrict__ out)
{
    const int b    = blockIdx.x;
    const int base = b * Tn;
    const int tid  = threadIdx.x;
    const int wv   = tid >> 6;
    const int L    = tid & 63;
    const int L15  = L & 15, quad = L >> 4;

    __shared__ __align__(16) unsigned short reads_bf[208][136];  // 56.6 KB (pad: 272 B row stride)
    __shared__ float red[2][WVS][8][64];                         // 41.0 KB

    const bfrag* Bea = (const bfrag*)BeaU;
    const bfrag* Bkm = (const bfrag*)BkmU;
    const bfrag* Bf0 = (const bfrag*)Bf0U;

    // ================= Phase A =================
    for (int tile = wv; tile < 13; tile += WVS) {
        const int tok0 = tile * 16;
        const int rowA = tok0 + L15;                     // A-frag token row (may be >=200 on tile 12)
        const int gA   = base + ((rowA < Tn) ? rowA : (Tn - 1));
        const int trow = tok0 + quad * 4;                // D rows are trow+reg

        const int s  = skill[gA];
        const int an = answer[gA];
        const int ax = (an == 2) ? 1 : an;
        const float* vp = v_emb + ((size_t)(s + NUMC * ax)) * DS + quad * 8;
        const float* kk = k_emb + (size_t)s * DS + quad * 8;
        bfrag Vf[4], Kf[4];
        #pragma unroll
        for (int ki = 0; ki < 4; ki++) {
            const f32x4* a = (const f32x4*)(vp + ki * 32);
            Vf[ki] = mk_frag(a[0], a[1]);
            const f32x4* c = (const f32x4*)(kk + ki * 32);
            Kf[ki] = mk_frag(c[0], c[1]);
        }

        bfrag bfA[4][4], bfB[4][4];
        load_group(Bea, 0, L, bfA);
        f32x4 acc[4];

        #define ZACC { _Pragma("unroll") for (int t_ = 0; t_ < 4; t_++) acc[t_] = (f32x4){0.f,0.f,0.f,0.f}; }
        // G0: e cols 0-63
        ZACC mfma_group(Vf, bfA, acc); load_group(Bea, 4, L, bfB);
        #pragma unroll
        for (int t = 0; t < 4; t++) {
            const int n = t * 16 + L15; const float bias = eB[n];
            #pragma unroll
            for (int reg = 0; reg < 4; reg++)
                if (trow + reg < Tn) e_buf[(size_t)(base + trow + reg) * DS + n] = fast_sigmoid(acc[t][reg] + bias);
        }
        // G1: e cols 64-127
        ZACC mfma_group(Vf, bfB, acc); load_group(Bea, 8, L, bfA);
        #pragma unroll
        for (int t = 0; t < 4; t++) {
            const int n = 64 + t * 16 + L15; const float bias = eB[n];
            #pragma unroll
            for (int reg = 0; reg < 4; reg++)
                if (trow + reg < Tn) e_buf[(size_t)(base + trow + reg) * DS + n] = fast_sigmoid(acc[t][reg] + bias);
        }
        // G2: a cols 0-63
        ZACC mfma_group(Vf, bfA, acc); load_group(Bea, 12, L, bfB);
        #pragma unroll
        for (int t = 0; t < 4; t++) {
            const int n = t * 16 + L15; const float bias = aB[n];
            #pragma unroll
            for (int reg = 0; reg < 4; reg++)
                if (trow + reg < Tn) a_buf[(size_t)(base + trow + reg) * DS + n] = fast_tanh(acc[t][reg] + bias);
        }
        // G3: a cols 64-127
        ZACC mfma_group(Vf, bfB, acc); load_group(Bkm, 0, L, bfA);
        #pragma unroll
        for (int t = 0; t < 4; t++) {
            const int n = 64 + t * 16 + L15; const float bias = aB[n];
            #pragma unroll
            for (int reg = 0; reg < 4; reg++)
                if (trow + reg < Tn) a_buf[(size_t)(base + trow + reg) * DS + n] = fast_tanh(acc[t][reg] + bias);
        }
        // G4: kp cols 0-63
        ZACC mfma_group(Kf, bfA, acc); load_group(Bkm, 4, L, bfB);
        #pragma unroll
        for (int t = 0; t < 4; t++) {
            const int n = t * 16 + L15;
            #pragma unroll
            for (int reg = 0; reg < 4; reg++)
                if (trow + reg < Tn) kp_buf[(size_t)(base + trow + reg) * DS + n] = acc[t][reg];
        }
        // G5: kp cols 64-127
        ZACC mfma_group(Kf, bfB, acc); load_group(Bkm, 8, L, bfA);
        #pragma unroll
        for (int t = 0; t < 4; t++) {
            const int n = 64 + t * 16 + L15;
            #pragma unroll
            for (int reg = 0; reg < 4; reg++)
                if (trow + reg < Tn) kp_buf[(size_t)(base + trow + reg) * DS + n] = acc[t][reg];
        }
        // G6: w logits cols 0-63 (valid < 50), wave-parallel softmax per row
        ZACC mfma_group(Kf, bfA, acc);
        #pragma unroll
        for (int reg = 0; reg < 4; reg++) {
            float m = -1e30f;
            #pragma unroll
            for (int t = 0; t < 4; t++) { const int c = t * 16 + L15; if (c < SM) m = fmaxf(m, acc[t][reg]); }
            #pragma unroll
            for (int msk = 1; msk <= 8; msk <<= 1) m = fmaxf(m, __shfl_xor(m, msk));
            float ex[4]; float ssum = 0.f;
            #pragma unroll
            for (int t = 0; t < 4; t++) {
                const int c = t * 16 + L15;
                ex[t] = (c < SM) ? fast_exp(acc[t][reg] - m) : 0.f;
                ssum += ex[t];
            }
            #pragma unroll
            for (int msk = 1; msk <= 8; msk <<= 1) ssum += __shfl_xor(ssum, msk);
            const float inv = fast_rcp(ssum);
            if (trow + reg < Tn) {
                float* wp = w_buf + (size_t)(base + trow + reg) * SM;
                #pragma unroll
                for (int t = 0; t < 4; t++) { const int c = t * 16 + L15; if (c < SM) wp[c] = ex[t] * inv; }
            }
        }
        #undef ZACC
    }
    __syncthreads();   // e,a,w,kp visible block-wide (global, same block)

    // ================= Phase B: scan =================
    {
        const int dh = wv / 5;           // d-half
        const int mg = wv % 5;           // m-group
        const int m0 = mg * MPG;
        const int d  = dh * 64 + L;

        float Mv[MPG];
        #pragma unroll
        for (int m = 0; m < MPG; m++) Mv[m] = Mv0[(size_t)(m0 + m) * DS + d];

        float se[4][2], sa[4][2], sw[4][2][MPG];

        #define LOADST(ST, T)                                                      \
            { const int tc_ = ((T) < Tn) ? (T) : 0;                                \
              _Pragma("unroll")                                                    \
              for (int q_ = 0; q_ < 2; q_++) {                                     \
                  const int tf_ = base + tc_ + q_;                                 \
                  se[ST][q_] = e_buf[(size_t)tf_*DS + d];                          \
                  sa[ST][q_] = a_buf[(size_t)tf_*DS + d];                          \
                  _Pragma("unroll")                                                \
                  for (int m_ = 0; m_ < MPG; m_++)                                 \
                      sw[ST][q_][m_] = w_buf[(size_t)tf_*SM + m0 + m_];            \
              } }

        LOADST(0, 0) LOADST(1, 2) LOADST(2, 4) LOADST(3, 6)

        for (int i = 0; i < 25; i++) {
            const int tb = i * 8;
            const int p  = i & 1;
            #pragma unroll
            for (int sub = 0; sub < 4; sub++) {
                const int t0 = tb + sub * 2;
                #pragma unroll
                for (int q = 0; q < 2; q++) {
                    const float ev = se[sub][q], av = sa[sub][q];
                    float rd = 0.f;
                    #pragma unroll
                    for (int m = 0; m < MPG; m++) {
                        const float wm = sw[sub][q][m];
                        rd = fmaf(wm, Mv[m], rd);                               // read uses OLD Mv
                        Mv[m] = fmaf(-wm, fmaf(ev, Mv[m], -av), Mv[m]);         // Mv*(1-w*e)+w*a
                    }
                    red[p][wv][sub * 2 + q][L] = rd;
                }
                LOADST(sub, t0 + 8)
            }
            __syncthreads();
            // cross-wave reduce: 1024 outputs (8 t x 128 d) over 640 threads.
            // Safe w/o 2nd barrier: red[p] is re-written at tile i+2 only after the
            // NEXT barrier, by which time every thread finished reading red[p] here.
            for (int o = tid; o < 1024; o += 640) {
                const int tt = o >> 7, dd = o & 127;
                const int dh2 = dd >> 6, d6 = dd & 63;
                float s = red[p][dh2 * 5 + 0][tt][d6];
                #pragma unroll
                for (int g = 1; g < 5; g++) s += red[p][dh2 * 5 + g][tt][d6];
                reads_bf[tb + tt][dd] = f2bf(s);
            }
        }
        #undef LOADST
    }
    __syncthreads();   // reads_bf complete

    // ================= Phase D: f-GEMM + pred =================
    for (int tile = wv; tile < 13; tile += WVS) {
        const int tok0 = tile * 16;
        const int trow = tok0 + quad * 4;

        bfrag Rf[4];
        #pragma unroll
        for (int ki = 0; ki < 4; ki++)
            Rf[ki] = *reinterpret_cast<const bfrag*>(&reads_bf[tok0 + L15][ki * 32 + quad * 8]);

        bfrag bfA[4][4], bfB[4][4];
        load_group(Bf0, 0, L, bfA);
        load_group(Bf0, 4, L, bfB);

        float f[4][8];   // [reg][nt]
        f32x4 acc[4];

        #pragma unroll
        for (int t = 0; t < 4; t++) acc[t] = (f32x4){0.f,0.f,0.f,0.f};
        mfma_group(Rf, bfA, acc);
        #pragma unroll
        for (int t = 0; t < 4; t++) {
            const int n = t * 16 + L15;
            const float fb = fB[n];
            #pragma unroll
            for (int reg = 0; reg < 4; reg++) {
                const int lrow = (trow + reg < Tn) ? (trow + reg) : (Tn - 1);
                f[reg][t] = fast_tanh(acc[t][reg] + kp_buf[(size_t)(base + lrow) * DS + n] + fb);
            }
        }

        #pragma unroll
        for (int t = 0; t < 4; t++) acc[t] = (f32x4){0.f,0.f,0.f,0.f};
        mfma_group(Rf, bfB, acc);
        #pragma unroll
        for (int t = 0; t < 4; t++) {
            const int n = (4 + t) * 16 + L15;
            const float fb = fB[n];
            #pragma unroll
            for (int reg = 0; reg < 4; reg++) {
                const int lrow = (trow + reg < Tn) ? (trow + reg) : (Tn - 1);
                f[reg][4 + t] = fast_tanh(acc[t][reg] + kp_buf[(size_t)(base + lrow) * DS + n] + fb);
            }
        }

        // pred: per D-row token, dot(f, pW[ix]) reduced over the 16 lanes (L15)
        #pragma unroll
        for (int reg = 0; reg < 4; reg++) {
            const int t_in = trow + reg;
            const bool act = (t_in < Tn - 1);
            int sn = 0, ix = 0;
            float contrib = 0.f;
            if (act) {
                sn = skill[base + t_in + 1];
                ix = (sn < NUMC) ? sn : (NUMC - 1);
                const float* pr = pW + (size_t)ix * DS + L15;
                #pragma unroll
                for (int nt = 0; nt < 8; nt++)
                    contrib = fmaf(f[reg][nt], pr[nt * 16], contrib);
            }
            #pragma unroll
            for (int msk = 1; msk <= 8; msk <<= 1)
                contrib += __shfl_xor(contrib, msk);
            if (act && L15 == 0) {
                const float val = contrib + pB[ix];
                const float prd = (sn < NUMC) ? fast_sigmoid(val) : 0.f;
                out[(size_t)b * (Tn - 1) + t_in] = prd;
            }
        }
    }
}

extern "C" void kernel_launch(void* const* d_in, const int* in_sizes, int n_in,
                              void* d_out, int out_size, void* d_ws, size_t ws_size,
                              hipStream_t stream)
{
    const int*   skill  = (const int*)  d_in[0];
    const int*   answer = (const int*)  d_in[1];
    const float* k_emb  = (const float*)d_in[2];
    const float* v_emb  = (const float*)d_in[3];
    const float* Mk     = (const float*)d_in[4];
    const float* Mv0    = (const float*)d_in[5];
    const float* f_W    = (const float*)d_in[6];
    const float* f_b    = (const float*)d_in[7];
    const float* p_W    = (const float*)d_in[8];
    const float* p_b    = (const float*)d_in[9];
    const float* e_W    = (const float*)d_in[10];
    const float* e_b    = (const float*)d_in[11];
    const float* a_W    = (const float*)d_in[12];
    const float* a_b    = (const float*)d_in[13];
    float* out = (float*)d_out;

    float* ws     = (float*)d_ws;
    float* w_buf  = ws;                                  // NTOK*SM
    float* e_buf  = w_buf  + (size_t)NTOK*SM;
    float* a_buf  = e_buf  + (size_t)NTOK*DS;
    float* kp_buf = a_buf  + (size_t)NTOK*DS;
    unsigned int* BeaU = (unsigned int*)(kp_buf + (size_t)NTOK*DS);
    unsigned int* BkmU = BeaU + 4096 * 4;
    unsigned int* Bf0U = BkmU + 3072 * 4;

    k0_cast<<<36, 256, 0, stream>>>(e_W, a_W, f_W, Mk, BeaU, BkmU, Bf0U);
    kf_fused<<<Bsz, 640, 0, stream>>>(skill, answer, k_emb, v_emb,
        BeaU, BkmU, Bf0U, e_b, a_b, Mv0, f_b, p_W, p_b,
        e_buf, a_buf, w_buf, kp_buf, out);
}

// Round 3
// 172.960 us; speedup vs baseline: 1.6800x; 1.6800x over previous
//
#include <hip/hip_runtime.h>
#include <math.h>

#define Bsz 64
#define Tn 200
#define NUMC 2000
#define DS 128
#define SM 50
#define NTOK (Bsz*Tn)
#define WG2 25       // m-groups in scan (one wave each)
#define MPG2 2       // m per group (WG2*MPG2 == SM)

typedef __attribute__((ext_vector_type(8))) short bfrag;
typedef __attribute__((ext_vector_type(4))) float f32x4;
typedef __attribute__((ext_vector_type(4))) unsigned int u32x4;
typedef __attribute__((ext_vector_type(2))) unsigned int u32x2;

__device__ __forceinline__ unsigned short f2bf(float x) {
    unsigned int u = __builtin_bit_cast(unsigned int, x);
    u = u + 0x7fffu + ((u >> 16) & 1u);   // RNE
    return (unsigned short)(u >> 16);
}
__device__ __forceinline__ unsigned int pack2(float a, float b) {
    return (unsigned int)f2bf(a) | ((unsigned int)f2bf(b) << 16);
}
__device__ __forceinline__ bfrag mk_frag(f32x4 x, f32x4 y) {
    u32x4 t;
    t[0] = pack2(x[0], x[1]); t[1] = pack2(x[2], x[3]);
    t[2] = pack2(y[0], y[1]); t[3] = pack2(y[2], y[3]);
    return __builtin_bit_cast(bfrag, t);
}

// fast transcendentals: v_exp_f32 / v_rcp_f32 (~1e-6 rel err, invisible at bf16 grade)
__device__ __forceinline__ float fast_exp(float x)  { return __builtin_amdgcn_exp2f(x * 1.44269504f); }
__device__ __forceinline__ float fast_rcp(float x)  { return __builtin_amdgcn_rcpf(x); }
__device__ __forceinline__ float fast_sigmoid(float x) { return fast_rcp(1.f + fast_exp(-x)); }
__device__ __forceinline__ float fast_tanh(float x) { return 1.f - 2.f * fast_rcp(fast_exp(2.f * x) + 1.f); }

// ---------------- K0: cast weights into MFMA b-frag block layout ----------------
// lane L holds W[n = nt*16 + (L&15)][k = ki*32 + (L>>4)*8 + j], j=0..7.
// Bea: rows 0-127 = e_W, 128-255 = a_W          (16 n-tiles)
// Bkm: rows 0-127 = f_W[:,128:256], 128-177 = Mk, 178-191 = 0   (12 n-tiles)
// Bf0: rows 0-127 = f_W[:,0:128]                (8 n-tiles)
__global__ __launch_bounds__(256) void k0_cast(
    const float* __restrict__ eW, const float* __restrict__ aW,
    const float* __restrict__ fW, const float* __restrict__ Mk,
    unsigned int* __restrict__ BeaU, unsigned int* __restrict__ BkmU,
    unsigned int* __restrict__ Bf0U)
{
    const int g = blockIdx.x * 256 + threadIdx.x;
    if (g >= 9216) return;
    int gm, mat;
    unsigned int* dst;
    if (g < 4096)      { mat = 0; gm = g;        dst = BeaU; }
    else if (g < 7168) { mat = 1; gm = g - 4096; dst = BkmU; }
    else               { mat = 2; gm = g - 7168; dst = Bf0U; }
    const int nt = gm >> 8, r = gm & 255, ki = r >> 6, L = r & 63;
    const int n = nt * 16 + (L & 15);
    const int k = ki * 32 + (L >> 4) * 8;

    const float* src = nullptr;
    if (mat == 0) {
        src = (n < 128) ? (eW + (size_t)n * DS + k) : (aW + (size_t)(n - 128) * DS + k);
    } else if (mat == 1) {
        if (n < 128)      src = fW + (size_t)n * (2 * DS) + DS + k;
        else if (n < 128 + SM) src = Mk + (size_t)(n - 128) * DS + k;
    } else {
        src = fW + (size_t)n * (2 * DS) + k;
    }
    float v[8];
    #pragma unroll
    for (int j = 0; j < 8; j++) v[j] = src ? src[j] : 0.f;
    u32x4 o;
    o[0] = pack2(v[0], v[1]); o[1] = pack2(v[2], v[3]);
    o[2] = pack2(v[4], v[5]); o[3] = pack2(v[6], v[7]);
    ((u32x4*)dst)[gm] = o;
}

// ---------------- K1: 7 single-purpose waves per 16-token tile (5600 blocks) ----------------
// role 0/1: e cols 0-63/64-127 (V @ Bea[0:8],  sigmoid)
// role 2/3: a cols 0-63/64-127 (V @ Bea[8:16], tanh)
// role 4/5: kp cols 0-63/64-127 (K @ Bkm[0:8])
// role 6  : w logits (K @ Bkm[8:12]) + wave-parallel softmax
__global__ __launch_bounds__(64, 4) void k1_gemm(
    const int* __restrict__ skill, const int* __restrict__ answer,
    const float* __restrict__ k_emb, const float* __restrict__ v_emb,
    const unsigned int* __restrict__ BeaU, const unsigned int* __restrict__ BkmU,
    const float* __restrict__ eB, const float* __restrict__ aB,
    float* __restrict__ w_buf, float* __restrict__ e_buf,
    float* __restrict__ a_buf, float* __restrict__ kp_buf)
{
    const int bid = blockIdx.x;
    const int tile = bid / 7, role = bid % 7;
    const int L = threadIdx.x, L15 = L & 15, quad = L >> 4;
    const int tok0 = tile * 16;
    const int tokA = tok0 + L15;
    const int row0 = tok0 + quad * 4;

    const int s = skill[tokA];
    const float* ap;
    if (role < 4) {
        const int an = answer[tokA];
        const int ax = (an == 2) ? 1 : an;
        ap = v_emb + ((size_t)(s + NUMC * ax)) * DS + quad * 8;
    } else {
        ap = k_emb + (size_t)s * DS + quad * 8;
    }
    bfrag Af[4];
    #pragma unroll
    for (int ki = 0; ki < 4; ki++) {
        const f32x4* a4 = (const f32x4*)(ap + ki * 32);
        Af[ki] = mk_frag(a4[0], a4[1]);
    }

    const bfrag* Bp = (role < 4) ? (const bfrag*)BeaU : (const bfrag*)BkmU;
    const int g0 = (role < 4) ? role * 4 : (role - 4) * 4;

    f32x4 acc[4];
    #pragma unroll
    for (int t = 0; t < 4; t++) acc[t] = (f32x4){0.f,0.f,0.f,0.f};

    // B in two 2-tile halves to keep VGPRs under the (64,4) cap
    #pragma unroll
    for (int half = 0; half < 2; half++) {
        bfrag bh[2][4];
        #pragma unroll
        for (int tt = 0; tt < 2; tt++)
            #pragma unroll
            for (int ki = 0; ki < 4; ki++)
                bh[tt][ki] = Bp[(size_t)((g0 + half * 2 + tt) * 4 + ki) * 64 + L];
        #pragma unroll
        for (int ki = 0; ki < 4; ki++)
            #pragma unroll
            for (int tt = 0; tt < 2; tt++)
                acc[half * 2 + tt] = __builtin_amdgcn_mfma_f32_16x16x32_bf16(
                    Af[ki], bh[tt][ki], acc[half * 2 + tt], 0, 0, 0);
    }

    if (role == 6) {
        #pragma unroll
        for (int reg = 0; reg < 4; reg++) {
            float mx = -1e30f;
            #pragma unroll
            for (int t = 0; t < 4; t++) { const int c = t * 16 + L15; if (c < SM) mx = fmaxf(mx, acc[t][reg]); }
            #pragma unroll
            for (int msk = 1; msk <= 8; msk <<= 1) mx = fmaxf(mx, __shfl_xor(mx, msk));
            float ex[4]; float ssum = 0.f;
            #pragma unroll
            for (int t = 0; t < 4; t++) {
                const int c = t * 16 + L15;
                ex[t] = (c < SM) ? fast_exp(acc[t][reg] - mx) : 0.f;
                ssum += ex[t];
            }
            #pragma unroll
            for (int msk = 1; msk <= 8; msk <<= 1) ssum += __shfl_xor(ssum, msk);
            const float inv = fast_rcp(ssum);
            float* wp = w_buf + (size_t)(row0 + reg) * SM;
            #pragma unroll
            for (int t = 0; t < 4; t++) { const int c = t * 16 + L15; if (c < SM) wp[c] = ex[t] * inv; }
        }
    } else {
        const int nb = (role & 1) * 64;
        float* obuf = (role < 2) ? e_buf : (role < 4) ? a_buf : kp_buf;
        const float* bias = (role < 2) ? eB : aB;
        #pragma unroll
        for (int t = 0; t < 4; t++) {
            const int n = nb + t * 16 + L15;
            const float bv = (role < 4) ? bias[n] : 0.f;
            #pragma unroll
            for (int reg = 0; reg < 4; reg++) {
                float v = acc[t][reg] + bv;
                if (role < 2)      v = fast_sigmoid(v);
                else if (role < 4) v = fast_tanh(v);
                obuf[(size_t)(row0 + reg) * DS + n] = v;
            }
        }
    }
}

// ---------------- K2: scan; (b, d-half, m-group) waves; WG2=25 -> 3200 waves ----------------
__global__ __launch_bounds__(64, 4) void k2_scan(
    const float* __restrict__ w_buf, const float* __restrict__ e_buf,
    const float* __restrict__ a_buf, const float* __restrict__ Mv0,
    float* __restrict__ part_buf)
{
    const int bi   = blockIdx.x;
    const int b    = bi / (2*WG2);
    const int r    = bi % (2*WG2);
    const int dh   = r / WG2;
    const int mg   = r % WG2;
    const int lane = threadIdx.x;
    const int d    = dh*64 + lane;
    const int m0   = mg * MPG2;
    const int base = b * Tn;

    float Mv[MPG2];
    #pragma unroll
    for (int m = 0; m < MPG2; m++) Mv[m] = Mv0[(size_t)(m0+m)*DS + d];

    float* pout = part_buf + (size_t)mg * NTOK * DS;

    float se[4][2], sa[4][2], sw[4][2][MPG2];

    #define LOADST(ST, T)                                                      \
        { const int tc_ = ((T) < Tn) ? (T) : 0;                                \
          _Pragma("unroll")                                                    \
          for (int q_ = 0; q_ < 2; q_++) {                                     \
              const int tf_ = base + tc_ + q_;                                 \
              se[ST][q_] = e_buf[(size_t)tf_*DS + d];                          \
              sa[ST][q_] = a_buf[(size_t)tf_*DS + d];                          \
              _Pragma("unroll")                                                \
              for (int m_ = 0; m_ < MPG2; m_++)                                \
                  sw[ST][q_][m_] = w_buf[(size_t)tf_*SM + m0 + m_];            \
          } }

    LOADST(0, 0) LOADST(1, 2) LOADST(2, 4) LOADST(3, 6)

    for (int i = 0; i < 25; i++) {
        const int tb = i * 8;
        #pragma unroll
        for (int sub = 0; sub < 4; sub++) {
            const int t0 = tb + sub * 2;
            #pragma unroll
            for (int q = 0; q < 2; q++) {
                const float ev = se[sub][q], av = sa[sub][q];
                float rd = 0.f;
                #pragma unroll
                for (int m = 0; m < MPG2; m++) {
                    const float wm = sw[sub][q][m];
                    rd = fmaf(wm, Mv[m], rd);                               // read uses OLD Mv
                    Mv[m] = fmaf(-wm, fmaf(ev, Mv[m], -av), Mv[m]);         // Mv*(1-w*e)+w*a
                }
                pout[(size_t)(base + t0 + q)*DS + d] = rd;
            }
            LOADST(sub, t0 + 8)
        }
    }
    #undef LOADST
}

// ---------------- K2b: streaming reduce of 25 partial slices -> bf16 reads ----------------
__global__ __launch_bounds__(256) void k2b_reduce(
    const float* __restrict__ part_buf, unsigned int* __restrict__ readsU)
{
    const int i = blockIdx.x * 256 + threadIdx.x;   // vec4 index, NTOK*DS/4 total
    const f32x4* p = (const f32x4*)part_buf;
    f32x4 s = p[i];
    #pragma unroll 4
    for (int g = 1; g < WG2; g++) s += p[(size_t)g * (NTOK*DS/4) + i];
    u32x2 o;
    o[0] = pack2(s[0], s[1]);
    o[1] = pack2(s[2], s[3]);
    ((u32x2*)readsU)[i] = o;
}

// ---------------- K3: 2-wave blocks (n-halves); f-GEMM + pred with LDS combine ----------------
__global__ __launch_bounds__(128, 2) void k3_gemm(
    const unsigned short* __restrict__ reads, const float* __restrict__ kp_buf,
    const unsigned int* __restrict__ Bf0U, const float* __restrict__ fB,
    const float* __restrict__ pW, const float* __restrict__ pB,
    const int* __restrict__ skill, float* __restrict__ out)
{
    const int tid = threadIdx.x;
    const int wv  = tid >> 6;          // n-half: 0 -> cols 0-63, 1 -> cols 64-127
    const int L   = tid & 63, L15 = L & 15, quad = L >> 4;
    const int tok0 = blockIdx.x * 16;
    const int tokA = tok0 + L15;
    const int row0 = tok0 + quad * 4;

    __shared__ float sm[2][16];

    // A-frags: final reads, already bf16 in frag element order
    bfrag Rf[4];
    #pragma unroll
    for (int ki = 0; ki < 4; ki++)
        Rf[ki] = *(const bfrag*)(reads + (size_t)tokA * DS + ki * 32 + quad * 8);

    const bfrag* Bf0 = (const bfrag*)Bf0U;
    const int g0 = wv * 4;

    f32x4 acc[4];
    #pragma unroll
    for (int t = 0; t < 4; t++) acc[t] = (f32x4){0.f,0.f,0.f,0.f};

    #pragma unroll
    for (int half = 0; half < 2; half++) {
        bfrag bh[2][4];
        #pragma unroll
        for (int tt = 0; tt < 2; tt++)
            #pragma unroll
            for (int ki = 0; ki < 4; ki++)
                bh[tt][ki] = Bf0[(size_t)((g0 + half * 2 + tt) * 4 + ki) * 64 + L];
        #pragma unroll
        for (int ki = 0; ki < 4; ki++)
            #pragma unroll
            for (int tt = 0; tt < 2; tt++)
                acc[half * 2 + tt] = __builtin_amdgcn_mfma_f32_16x16x32_bf16(
                    Rf[ki], bh[tt][ki], acc[half * 2 + tt], 0, 0, 0);
    }

    const int nb = wv * 64;
    float f[4][4];   // [reg][t]
    #pragma unroll
    for (int t = 0; t < 4; t++) {
        const int n = nb + t * 16 + L15;
        const float fb = fB[n];
        #pragma unroll
        for (int reg = 0; reg < 4; reg++)
            f[reg][t] = fast_tanh(acc[t][reg] + kp_buf[(size_t)(row0 + reg) * DS + n] + fb);
    }

    // pred partial: this wave's 64-dim contribution, reduced over the 16 lanes (L15)
    #pragma unroll
    for (int reg = 0; reg < 4; reg++) {
        const int tok = row0 + reg;
        const int t = tok % Tn;
        const bool act = (t < Tn - 1);
        float contrib = 0.f;
        if (act) {
            const int sn = skill[tok + 1];
            const int ix = (sn < NUMC) ? sn : (NUMC - 1);
            const float* pr = pW + (size_t)ix * DS + nb + L15;
            #pragma unroll
            for (int t4 = 0; t4 < 4; t4++)
                contrib = fmaf(f[reg][t4], pr[t4 * 16], contrib);
        }
        #pragma unroll
        for (int msk = 1; msk <= 8; msk <<= 1)
            contrib += __shfl_xor(contrib, msk);
        if (L15 == 0) sm[wv][quad * 4 + reg] = contrib;
    }
    __syncthreads();
    if (tid < 16) {
        const int tok = tok0 + tid;
        const int t = tok % Tn;
        if (t < Tn - 1) {
            const int sn = skill[tok + 1];
            const int ix = (sn < NUMC) ? sn : (NUMC - 1);
            const float val = sm[0][tid] + sm[1][tid] + pB[ix];
            out[(size_t)(tok / Tn) * (Tn - 1) + t] = (sn < NUMC) ? fast_sigmoid(val) : 0.f;
        }
    }
}

extern "C" void kernel_launch(void* const* d_in, const int* in_sizes, int n_in,
                              void* d_out, int out_size, void* d_ws, size_t ws_size,
                              hipStream_t stream)
{
    const int*   skill  = (const int*)  d_in[0];
    const int*   answer = (const int*)  d_in[1];
    const float* k_emb  = (const float*)d_in[2];
    const float* v_emb  = (const float*)d_in[3];
    const float* Mk     = (const float*)d_in[4];
    const float* Mv0    = (const float*)d_in[5];
    const float* f_W    = (const float*)d_in[6];
    const float* f_b    = (const float*)d_in[7];
    const float* p_W    = (const float*)d_in[8];
    const float* p_b    = (const float*)d_in[9];
    const float* e_W    = (const float*)d_in[10];
    const float* e_b    = (const float*)d_in[11];
    const float* a_W    = (const float*)d_in[12];
    const float* a_b    = (const float*)d_in[13];
    float* out = (float*)d_out;

    float* ws     = (float*)d_ws;
    float* w_buf  = ws;                                   // NTOK*SM
    float* e_buf  = w_buf  + (size_t)NTOK*SM;             // NTOK*DS
    float* a_buf  = e_buf  + (size_t)NTOK*DS;             // NTOK*DS
    float* kp_buf = a_buf  + (size_t)NTOK*DS;             // NTOK*DS
    float* part   = kp_buf + (size_t)NTOK*DS;             // WG2*NTOK*DS (~164 MB)
    unsigned short* reads = (unsigned short*)(part + (size_t)WG2*NTOK*DS);  // NTOK*DS bf16
    unsigned int* BeaU = (unsigned int*)(reads + (size_t)NTOK*DS);
    unsigned int* BkmU = BeaU + 4096 * 4;
    unsigned int* Bf0U = BkmU + 3072 * 4;

    k0_cast<<<36, 256, 0, stream>>>(e_W, a_W, f_W, Mk, BeaU, BkmU, Bf0U);
    k1_gemm<<<7*(NTOK/16), 64, 0, stream>>>(skill, answer, k_emb, v_emb,
        BeaU, BkmU, e_b, a_b, w_buf, e_buf, a_buf, kp_buf);
    k2_scan<<<Bsz*2*WG2, 64, 0, stream>>>(w_buf, e_buf, a_buf, Mv0, part);
    k2b_reduce<<<(NTOK*DS/4)/256, 256, 0, stream>>>(part, (unsigned int*)reads);
    k3_gemm<<<NTOK/16, 128, 0, stream>>>(reads, kp_buf, Bf0U, f_b,
        p_W, p_b, skill, out);
}

// Round 4
// 147.367 us; speedup vs baseline: 1.9717x; 1.1737x over previous
//
#include <hip/hip_runtime.h>
#include <math.h>

#define Bsz 64
#define Tn 200
#define NUMC 2000
#define DS 128
#define SM 50
#define NTOK (Bsz*Tn)
#define WVS 10       // waves per scan block (5 m-groups x 2 would-be; here 5 mg per dh)
#define MPG 10       // m per scan wave (5 groups x 10 = SM)

typedef __attribute__((ext_vector_type(8))) short bfrag;
typedef __attribute__((ext_vector_type(4))) float f32x4;
typedef __attribute__((ext_vector_type(4))) unsigned int u32x4;

__device__ __forceinline__ unsigned short f2bf(float x) {
    unsigned int u = __builtin_bit_cast(unsigned int, x);
    u = u + 0x7fffu + ((u >> 16) & 1u);   // RNE
    return (unsigned short)(u >> 16);
}
__device__ __forceinline__ unsigned int pack2(float a, float b) {
    return (unsigned int)f2bf(a) | ((unsigned int)f2bf(b) << 16);
}
__device__ __forceinline__ bfrag mk_frag(f32x4 x, f32x4 y) {
    u32x4 t;
    t[0] = pack2(x[0], x[1]); t[1] = pack2(x[2], x[3]);
    t[2] = pack2(y[0], y[1]); t[3] = pack2(y[2], y[3]);
    return __builtin_bit_cast(bfrag, t);
}

// fast transcendentals: v_exp_f32 / v_rcp_f32 (~1e-6 rel err, invisible at bf16 grade)
__device__ __forceinline__ float fast_exp(float x)  { return __builtin_amdgcn_exp2f(x * 1.44269504f); }
__device__ __forceinline__ float fast_rcp(float x)  { return __builtin_amdgcn_rcpf(x); }
__device__ __forceinline__ float fast_sigmoid(float x) { return fast_rcp(1.f + fast_exp(-x)); }
__device__ __forceinline__ float fast_tanh(float x) { return 1.f - 2.f * fast_rcp(fast_exp(2.f * x) + 1.f); }

// ---------------- K0: cast weights into MFMA b-frag block layout ----------------
// lane L holds W[n = nt*16 + (L&15)][k = ki*32 + (L>>4)*8 + j], j=0..7.
// Bea: rows 0-127 = e_W, 128-255 = a_W          (16 n-tiles)
// Bkm: rows 0-127 = f_W[:,128:256], 128-177 = Mk, 178-191 = 0   (12 n-tiles)
// Bf0: rows 0-127 = f_W[:,0:128]                (8 n-tiles)
__global__ __launch_bounds__(256) void k0_cast(
    const float* __restrict__ eW, const float* __restrict__ aW,
    const float* __restrict__ fW, const float* __restrict__ Mk,
    unsigned int* __restrict__ BeaU, unsigned int* __restrict__ BkmU,
    unsigned int* __restrict__ Bf0U)
{
    const int g = blockIdx.x * 256 + threadIdx.x;
    if (g >= 9216) return;
    int gm, mat;
    unsigned int* dst;
    if (g < 4096)      { mat = 0; gm = g;        dst = BeaU; }
    else if (g < 7168) { mat = 1; gm = g - 4096; dst = BkmU; }
    else               { mat = 2; gm = g - 7168; dst = Bf0U; }
    const int nt = gm >> 8, r = gm & 255, ki = r >> 6, L = r & 63;
    const int n = nt * 16 + (L & 15);
    const int k = ki * 32 + (L >> 4) * 8;

    const float* src = nullptr;
    if (mat == 0) {
        src = (n < 128) ? (eW + (size_t)n * DS + k) : (aW + (size_t)(n - 128) * DS + k);
    } else if (mat == 1) {
        if (n < 128)      src = fW + (size_t)n * (2 * DS) + DS + k;
        else if (n < 128 + SM) src = Mk + (size_t)(n - 128) * DS + k;
    } else {
        src = fW + (size_t)n * (2 * DS) + k;
    }
    float v[8];
    #pragma unroll
    for (int j = 0; j < 8; j++) v[j] = src ? src[j] : 0.f;
    u32x4 o;
    o[0] = pack2(v[0], v[1]); o[1] = pack2(v[2], v[3]);
    o[2] = pack2(v[4], v[5]); o[3] = pack2(v[6], v[7]);
    ((u32x4*)dst)[gm] = o;
}

// ---------------- K1: 7 single-purpose waves per 16-token tile (5600 blocks) ----------------
// role 0/1: e cols 0-63/64-127 (V @ Bea[0:8],  sigmoid)
// role 2/3: a cols 0-63/64-127 (V @ Bea[8:16], tanh)
// role 4/5: kp cols 0-63/64-127 (K @ Bkm[0:8])
// role 6  : w logits (K @ Bkm[8:12]) + wave-parallel softmax
__global__ __launch_bounds__(64, 4) void k1_gemm(
    const int* __restrict__ skill, const int* __restrict__ answer,
    const float* __restrict__ k_emb, const float* __restrict__ v_emb,
    const unsigned int* __restrict__ BeaU, const unsigned int* __restrict__ BkmU,
    const float* __restrict__ eB, const float* __restrict__ aB,
    float* __restrict__ w_buf, float* __restrict__ e_buf,
    float* __restrict__ a_buf, float* __restrict__ kp_buf)
{
    const int bid = blockIdx.x;
    const int tile = bid / 7, role = bid % 7;
    const int L = threadIdx.x, L15 = L & 15, quad = L >> 4;
    const int tok0 = tile * 16;
    const int tokA = tok0 + L15;
    const int row0 = tok0 + quad * 4;

    const int s = skill[tokA];
    const float* ap;
    if (role < 4) {
        const int an = answer[tokA];
        const int ax = (an == 2) ? 1 : an;
        ap = v_emb + ((size_t)(s + NUMC * ax)) * DS + quad * 8;
    } else {
        ap = k_emb + (size_t)s * DS + quad * 8;
    }
    bfrag Af[4];
    #pragma unroll
    for (int ki = 0; ki < 4; ki++) {
        const f32x4* a4 = (const f32x4*)(ap + ki * 32);
        Af[ki] = mk_frag(a4[0], a4[1]);
    }

    const bfrag* Bp = (role < 4) ? (const bfrag*)BeaU : (const bfrag*)BkmU;
    const int g0 = (role < 4) ? role * 4 : (role - 4) * 4;

    f32x4 acc[4];
    #pragma unroll
    for (int t = 0; t < 4; t++) acc[t] = (f32x4){0.f,0.f,0.f,0.f};

    // B in two 2-tile halves to keep VGPRs under the (64,4) cap
    #pragma unroll
    for (int half = 0; half < 2; half++) {
        bfrag bh[2][4];
        #pragma unroll
        for (int tt = 0; tt < 2; tt++)
            #pragma unroll
            for (int ki = 0; ki < 4; ki++)
                bh[tt][ki] = Bp[(size_t)((g0 + half * 2 + tt) * 4 + ki) * 64 + L];
        #pragma unroll
        for (int ki = 0; ki < 4; ki++)
            #pragma unroll
            for (int tt = 0; tt < 2; tt++)
                acc[half * 2 + tt] = __builtin_amdgcn_mfma_f32_16x16x32_bf16(
                    Af[ki], bh[tt][ki], acc[half * 2 + tt], 0, 0, 0);
    }

    if (role == 6) {
        #pragma unroll
        for (int reg = 0; reg < 4; reg++) {
            float mx = -1e30f;
            #pragma unroll
            for (int t = 0; t < 4; t++) { const int c = t * 16 + L15; if (c < SM) mx = fmaxf(mx, acc[t][reg]); }
            #pragma unroll
            for (int msk = 1; msk <= 8; msk <<= 1) mx = fmaxf(mx, __shfl_xor(mx, msk));
            float ex[4]; float ssum = 0.f;
            #pragma unroll
            for (int t = 0; t < 4; t++) {
                const int c = t * 16 + L15;
                ex[t] = (c < SM) ? fast_exp(acc[t][reg] - mx) : 0.f;
                ssum += ex[t];
            }
            #pragma unroll
            for (int msk = 1; msk <= 8; msk <<= 1) ssum += __shfl_xor(ssum, msk);
            const float inv = fast_rcp(ssum);
            float* wp = w_buf + (size_t)(row0 + reg) * SM;
            #pragma unroll
            for (int t = 0; t < 4; t++) { const int c = t * 16 + L15; if (c < SM) wp[c] = ex[t] * inv; }
        }
    } else {
        const int nb = (role & 1) * 64;
        float* obuf = (role < 2) ? e_buf : (role < 4) ? a_buf : kp_buf;
        const float* bias = (role < 2) ? eB : aB;
        #pragma unroll
        for (int t = 0; t < 4; t++) {
            const int n = nb + t * 16 + L15;
            const float bv = (role < 4) ? bias[n] : 0.f;
            #pragma unroll
            for (int reg = 0; reg < 4; reg++) {
                float v = acc[t][reg] + bv;
                if (role < 2)      v = fast_sigmoid(v);
                else if (role < 4) v = fast_tanh(v);
                obuf[(size_t)(row0 + reg) * DS + n] = v;
            }
        }
    }
}

// ---------------- K2: scan; block = (b, d-half), 10 waves (one per m-group of 10) ----------------
// Each wave runs the 4-stage prefetch-ring scan for its 10 m-slots; per 8-t tile the
// 10 partial reads are cross-wave summed in LDS (double-buffered -> 1 barrier/tile) and
// the FINAL reads are written directly as bf16 (the rounding point k3 consumes anyway).
// No part_buf, no k2b: write traffic 160 MB -> 3.2 MB.
__global__ __launch_bounds__(640) void k2_scan(
    const float* __restrict__ w_buf, const float* __restrict__ e_buf,
    const float* __restrict__ a_buf, const float* __restrict__ Mv0,
    unsigned short* __restrict__ reads)
{
    const int bi   = blockIdx.x;          // 0..127
    const int b    = bi >> 1;
    const int dh   = bi & 1;
    const int tid  = threadIdx.x;
    const int wv   = tid >> 6;            // 0..9 = m-group
    const int L    = tid & 63;
    const int d    = dh * 64 + L;
    const int m0   = wv * MPG;            // wait: 10 groups x 10 m = 100 > SM. See below.
    const int base = b * Tn;

    // 10 waves but only SM=50 m-slots: waves 0-4 take m [wv*10, wv*10+10) of this d-half;
    // waves 5-9 mirror for... no — all 10 waves needed for the 50 m of THIS (b,dh).
    // Use 5 m-groups x 10 m; waves 5-9 duplicate groups 0-4 on the second t-phase? Simpler:
    // 10 waves x 5 m each.
    const int mg   = wv;                  // 0..9, MPG_EFF = 5
    const int m0e  = mg * 5;

    __shared__ float red[2][WVS][8][64];  // 41 KB double-buffered partial-read tile

    float Mv[5];
    #pragma unroll
    for (int m = 0; m < 5; m++) Mv[m] = Mv0[(size_t)(m0e + m) * DS + d];

    float se[4][2], sa[4][2], sw[4][2][5];

    #define LOADST(ST, T)                                                      \
        { const int tc_ = ((T) < Tn) ? (T) : 0;                                \
          _Pragma("unroll")                                                    \
          for (int q_ = 0; q_ < 2; q_++) {                                     \
              const int tf_ = base + tc_ + q_;                                 \
              se[ST][q_] = e_buf[(size_t)tf_*DS + d];                          \
              sa[ST][q_] = a_buf[(size_t)tf_*DS + d];                          \
              _Pragma("unroll")                                                \
              for (int m_ = 0; m_ < 5; m_++)                                   \
                  sw[ST][q_][m_] = w_buf[(size_t)tf_*SM + m0e + m_];           \
          } }

    LOADST(0, 0) LOADST(1, 2) LOADST(2, 4) LOADST(3, 6)

    for (int i = 0; i < 25; i++) {
        const int tb = i * 8;
        const int p  = i & 1;
        #pragma unroll
        for (int sub = 0; sub < 4; sub++) {
            const int t0 = tb + sub * 2;
            #pragma unroll
            for (int q = 0; q < 2; q++) {
                const float ev = se[sub][q], av = sa[sub][q];
                float rd = 0.f;
                #pragma unroll
                for (int m = 0; m < 5; m++) {
                    const float wm = sw[sub][q][m];
                    rd = fmaf(wm, Mv[m], rd);                               // read uses OLD Mv
                    Mv[m] = fmaf(-wm, fmaf(ev, Mv[m], -av), Mv[m]);         // Mv*(1-w*e)+w*a
                }
                red[p][wv][sub * 2 + q][L] = rd;
            }
            LOADST(sub, t0 + 8)
        }
        __syncthreads();
        // cross-wave reduce: 512 outputs (8 t x 64 d) over 640 threads.
        // Safe w/o 2nd barrier: red[p] is re-written at tile i+2 only after the NEXT
        // barrier, by which time every thread finished reading red[p] here.
        if (tid < 512) {
            const int tt = tid >> 6, dd = tid & 63;
            float s = red[p][0][tt][dd];
            #pragma unroll
            for (int g = 1; g < WVS; g++) s += red[p][g][tt][dd];
            reads[(size_t)(base + tb + tt) * DS + dh * 64 + dd] = f2bf(s);
        }
    }
    #undef LOADST
}

// ---------------- K3: 2-wave blocks (n-halves); f-GEMM + pred with LDS combine ----------------
__global__ __launch_bounds__(128, 2) void k3_gemm(
    const unsigned short* __restrict__ reads, const float* __restrict__ kp_buf,
    const unsigned int* __restrict__ Bf0U, const float* __restrict__ fB,
    const float* __restrict__ pW, const float* __restrict__ pB,
    const int* __restrict__ skill, float* __restrict__ out)
{
    const int tid = threadIdx.x;
    const int wv  = tid >> 6;          // n-half: 0 -> cols 0-63, 1 -> cols 64-127
    const int L   = tid & 63, L15 = L & 15, quad = L >> 4;
    const int tok0 = blockIdx.x * 16;
    const int tokA = tok0 + L15;
    const int row0 = tok0 + quad * 4;

    __shared__ float sm[2][16];

    // A-frags: final reads, already bf16 in frag element order
    bfrag Rf[4];
    #pragma unroll
    for (int ki = 0; ki < 4; ki++)
        Rf[ki] = *(const bfrag*)(reads + (size_t)tokA * DS + ki * 32 + quad * 8);

    const bfrag* Bf0 = (const bfrag*)Bf0U;
    const int g0 = wv * 4;

    f32x4 acc[4];
    #pragma unroll
    for (int t = 0; t < 4; t++) acc[t] = (f32x4){0.f,0.f,0.f,0.f};

    #pragma unroll
    for (int half = 0; half < 2; half++) {
        bfrag bh[2][4];
        #pragma unroll
        for (int tt = 0; tt < 2; tt++)
            #pragma unroll
            for (int ki = 0; ki < 4; ki++)
                bh[tt][ki] = Bf0[(size_t)((g0 + half * 2 + tt) * 4 + ki) * 64 + L];
        #pragma unroll
        for (int ki = 0; ki < 4; ki++)
            #pragma unroll
            for (int tt = 0; tt < 2; tt++)
                acc[half * 2 + tt] = __builtin_amdgcn_mfma_f32_16x16x32_bf16(
                    Rf[ki], bh[tt][ki], acc[half * 2 + tt], 0, 0, 0);
    }

    const int nb = wv * 64;
    float f[4][4];   // [reg][t]
    #pragma unroll
    for (int t = 0; t < 4; t++) {
        const int n = nb + t * 16 + L15;
        const float fb = fB[n];
        #pragma unroll
        for (int reg = 0; reg < 4; reg++)
            f[reg][t] = fast_tanh(acc[t][reg] + kp_buf[(size_t)(row0 + reg) * DS + n] + fb);
    }

    // pred partial: this wave's 64-dim contribution, reduced over the 16 lanes (L15)
    #pragma unroll
    for (int reg = 0; reg < 4; reg++) {
        const int tok = row0 + reg;
        const int t = tok % Tn;
        const bool act = (t < Tn - 1);
        float contrib = 0.f;
        if (act) {
            const int sn = skill[tok + 1];
            const int ix = (sn < NUMC) ? sn : (NUMC - 1);
            const float* pr = pW + (size_t)ix * DS + nb + L15;
            #pragma unroll
            for (int t4 = 0; t4 < 4; t4++)
                contrib = fmaf(f[reg][t4], pr[t4 * 16], contrib);
        }
        #pragma unroll
        for (int msk = 1; msk <= 8; msk <<= 1)
            contrib += __shfl_xor(contrib, msk);
        if (L15 == 0) sm[wv][quad * 4 + reg] = contrib;
    }
    __syncthreads();
    if (tid < 16) {
        const int tok = tok0 + tid;
        const int t = tok % Tn;
        if (t < Tn - 1) {
            const int sn = skill[tok + 1];
            const int ix = (sn < NUMC) ? sn : (NUMC - 1);
            const float val = sm[0][tid] + sm[1][tid] + pB[ix];
            out[(size_t)(tok / Tn) * (Tn - 1) + t] = (sn < NUMC) ? fast_sigmoid(val) : 0.f;
        }
    }
}

extern "C" void kernel_launch(void* const* d_in, const int* in_sizes, int n_in,
                              void* d_out, int out_size, void* d_ws, size_t ws_size,
                              hipStream_t stream)
{
    const int*   skill  = (const int*)  d_in[0];
    const int*   answer = (const int*)  d_in[1];
    const float* k_emb  = (const float*)d_in[2];
    const float* v_emb  = (const float*)d_in[3];
    const float* Mk     = (const float*)d_in[4];
    const float* Mv0    = (const float*)d_in[5];
    const float* f_W    = (const float*)d_in[6];
    const float* f_b    = (const float*)d_in[7];
    const float* p_W    = (const float*)d_in[8];
    const float* p_b    = (const float*)d_in[9];
    const float* e_W    = (const float*)d_in[10];
    const float* e_b    = (const float*)d_in[11];
    const float* a_W    = (const float*)d_in[12];
    const float* a_b    = (const float*)d_in[13];
    float* out = (float*)d_out;

    float* ws     = (float*)d_ws;
    float* w_buf  = ws;                                   // NTOK*SM
    float* e_buf  = w_buf  + (size_t)NTOK*SM;             // NTOK*DS
    float* a_buf  = e_buf  + (size_t)NTOK*DS;             // NTOK*DS
    float* kp_buf = a_buf  + (size_t)NTOK*DS;             // NTOK*DS
    unsigned short* reads = (unsigned short*)(kp_buf + (size_t)NTOK*DS);  // NTOK*DS bf16
    unsigned int* BeaU = (unsigned int*)(reads + (size_t)NTOK*DS);
    unsigned int* BkmU = BeaU + 4096 * 4;
    unsigned int* Bf0U = BkmU + 3072 * 4;

    k0_cast<<<36, 256, 0, stream>>>(e_W, a_W, f_W, Mk, BeaU, BkmU, Bf0U);
    k1_gemm<<<7*(NTOK/16), 64, 0, stream>>>(skill, answer, k_emb, v_emb,
        BeaU, BkmU, e_b, a_b, w_buf, e_buf, a_buf, kp_buf);
    k2_scan<<<Bsz*2, 640, 0, stream>>>(w_buf, e_buf, a_buf, Mv0, reads);
    k3_gemm<<<NTOK/16, 128, 0, stream>>>(reads, kp_buf, Bf0U, f_b,
        p_W, p_b, skill, out);
}

// Round 5
// 138.898 us; speedup vs baseline: 2.0920x; 1.0610x over previous
//
#include <hip/hip_runtime.h>
#include <math.h>

#define Bsz 64
#define Tn 200
#define NUMC 2000
#define DS 128
#define SM 50
#define NTOK (Bsz*Tn)
#define WVS 10       // waves per scan block (one 5-m group each)
#define CH 40        // t-chunk staged in LDS per double-buffer phase
#define NCH (Tn/CH)  // 5 chunks

typedef __attribute__((ext_vector_type(8))) short bfrag;
typedef __attribute__((ext_vector_type(4))) float f32x4;
typedef __attribute__((ext_vector_type(4))) unsigned int u32x4;

__device__ __forceinline__ unsigned short f2bf(float x) {
    unsigned int u = __builtin_bit_cast(unsigned int, x);
    u = u + 0x7fffu + ((u >> 16) & 1u);   // RNE
    return (unsigned short)(u >> 16);
}
__device__ __forceinline__ unsigned int pack2(float a, float b) {
    return (unsigned int)f2bf(a) | ((unsigned int)f2bf(b) << 16);
}
__device__ __forceinline__ bfrag mk_frag(f32x4 x, f32x4 y) {
    u32x4 t;
    t[0] = pack2(x[0], x[1]); t[1] = pack2(x[2], x[3]);
    t[2] = pack2(y[0], y[1]); t[3] = pack2(y[2], y[3]);
    return __builtin_bit_cast(bfrag, t);
}

// fast transcendentals: v_exp_f32 / v_rcp_f32 (~1e-6 rel err, invisible at bf16 grade)
__device__ __forceinline__ float fast_exp(float x)  { return __builtin_amdgcn_exp2f(x * 1.44269504f); }
__device__ __forceinline__ float fast_rcp(float x)  { return __builtin_amdgcn_rcpf(x); }
__device__ __forceinline__ float fast_sigmoid(float x) { return fast_rcp(1.f + fast_exp(-x)); }
__device__ __forceinline__ float fast_tanh(float x) { return 1.f - 2.f * fast_rcp(fast_exp(2.f * x) + 1.f); }

// ---------------- K0: cast weights into MFMA b-frag block layout ----------------
// lane L holds W[n = nt*16 + (L&15)][k = ki*32 + (L>>4)*8 + j], j=0..7.
// Bea: rows 0-127 = e_W, 128-255 = a_W          (16 n-tiles)
// Bkm: rows 0-127 = f_W[:,128:256], 128-177 = Mk, 178-191 = 0   (12 n-tiles)
// Bf0: rows 0-127 = f_W[:,0:128]                (8 n-tiles)
__global__ __launch_bounds__(256) void k0_cast(
    const float* __restrict__ eW, const float* __restrict__ aW,
    const float* __restrict__ fW, const float* __restrict__ Mk,
    unsigned int* __restrict__ BeaU, unsigned int* __restrict__ BkmU,
    unsigned int* __restrict__ Bf0U)
{
    const int g = blockIdx.x * 256 + threadIdx.x;
    if (g >= 9216) return;
    int gm, mat;
    unsigned int* dst;
    if (g < 4096)      { mat = 0; gm = g;        dst = BeaU; }
    else if (g < 7168) { mat = 1; gm = g - 4096; dst = BkmU; }
    else               { mat = 2; gm = g - 7168; dst = Bf0U; }
    const int nt = gm >> 8, r = gm & 255, ki = r >> 6, L = r & 63;
    const int n = nt * 16 + (L & 15);
    const int k = ki * 32 + (L >> 4) * 8;

    const float* src = nullptr;
    if (mat == 0) {
        src = (n < 128) ? (eW + (size_t)n * DS + k) : (aW + (size_t)(n - 128) * DS + k);
    } else if (mat == 1) {
        if (n < 128)      src = fW + (size_t)n * (2 * DS) + DS + k;
        else if (n < 128 + SM) src = Mk + (size_t)(n - 128) * DS + k;
    } else {
        src = fW + (size_t)n * (2 * DS) + k;
    }
    float v[8];
    #pragma unroll
    for (int j = 0; j < 8; j++) v[j] = src ? src[j] : 0.f;
    u32x4 o;
    o[0] = pack2(v[0], v[1]); o[1] = pack2(v[2], v[3]);
    o[2] = pack2(v[4], v[5]); o[3] = pack2(v[6], v[7]);
    ((u32x4*)dst)[gm] = o;
}

// ---------------- K1: 7 single-purpose waves per 16-token tile (5600 blocks) ----------------
// role 0/1: e cols 0-63/64-127 (V @ Bea[0:8],  sigmoid)
// role 2/3: a cols 0-63/64-127 (V @ Bea[8:16], tanh)
// role 4/5: kp cols 0-63/64-127 (K @ Bkm[0:8])
// role 6  : w logits (K @ Bkm[8:12]) + wave-parallel softmax
__global__ __launch_bounds__(64, 4) void k1_gemm(
    const int* __restrict__ skill, const int* __restrict__ answer,
    const float* __restrict__ k_emb, const float* __restrict__ v_emb,
    const unsigned int* __restrict__ BeaU, const unsigned int* __restrict__ BkmU,
    const float* __restrict__ eB, const float* __restrict__ aB,
    float* __restrict__ w_buf, float* __restrict__ e_buf,
    float* __restrict__ a_buf, float* __restrict__ kp_buf)
{
    const int bid = blockIdx.x;
    const int tile = bid / 7, role = bid % 7;
    const int L = threadIdx.x, L15 = L & 15, quad = L >> 4;
    const int tok0 = tile * 16;
    const int tokA = tok0 + L15;
    const int row0 = tok0 + quad * 4;

    const int s = skill[tokA];
    const float* ap;
    if (role < 4) {
        const int an = answer[tokA];
        const int ax = (an == 2) ? 1 : an;
        ap = v_emb + ((size_t)(s + NUMC * ax)) * DS + quad * 8;
    } else {
        ap = k_emb + (size_t)s * DS + quad * 8;
    }
    bfrag Af[4];
    #pragma unroll
    for (int ki = 0; ki < 4; ki++) {
        const f32x4* a4 = (const f32x4*)(ap + ki * 32);
        Af[ki] = mk_frag(a4[0], a4[1]);
    }

    const bfrag* Bp = (role < 4) ? (const bfrag*)BeaU : (const bfrag*)BkmU;
    const int g0 = (role < 4) ? role * 4 : (role - 4) * 4;

    f32x4 acc[4];
    #pragma unroll
    for (int t = 0; t < 4; t++) acc[t] = (f32x4){0.f,0.f,0.f,0.f};

    // B in two 2-tile halves to keep VGPRs under the (64,4) cap
    #pragma unroll
    for (int half = 0; half < 2; half++) {
        bfrag bh[2][4];
        #pragma unroll
        for (int tt = 0; tt < 2; tt++)
            #pragma unroll
            for (int ki = 0; ki < 4; ki++)
                bh[tt][ki] = Bp[(size_t)((g0 + half * 2 + tt) * 4 + ki) * 64 + L];
        #pragma unroll
        for (int ki = 0; ki < 4; ki++)
            #pragma unroll
            for (int tt = 0; tt < 2; tt++)
                acc[half * 2 + tt] = __builtin_amdgcn_mfma_f32_16x16x32_bf16(
                    Af[ki], bh[tt][ki], acc[half * 2 + tt], 0, 0, 0);
    }

    if (role == 6) {
        #pragma unroll
        for (int reg = 0; reg < 4; reg++) {
            float mx = -1e30f;
            #pragma unroll
            for (int t = 0; t < 4; t++) { const int c = t * 16 + L15; if (c < SM) mx = fmaxf(mx, acc[t][reg]); }
            #pragma unroll
            for (int msk = 1; msk <= 8; msk <<= 1) mx = fmaxf(mx, __shfl_xor(mx, msk));
            float ex[4]; float ssum = 0.f;
            #pragma unroll
            for (int t = 0; t < 4; t++) {
                const int c = t * 16 + L15;
                ex[t] = (c < SM) ? fast_exp(acc[t][reg] - mx) : 0.f;
                ssum += ex[t];
            }
            #pragma unroll
            for (int msk = 1; msk <= 8; msk <<= 1) ssum += __shfl_xor(ssum, msk);
            const float inv = fast_rcp(ssum);
            float* wp = w_buf + (size_t)(row0 + reg) * SM;
            #pragma unroll
            for (int t = 0; t < 4; t++) { const int c = t * 16 + L15; if (c < SM) wp[c] = ex[t] * inv; }
        }
    } else {
        const int nb = (role & 1) * 64;
        float* obuf = (role < 2) ? e_buf : (role < 4) ? a_buf : kp_buf;
        const float* bias = (role < 2) ? eB : aB;
        #pragma unroll
        for (int t = 0; t < 4; t++) {
            const int n = nb + t * 16 + L15;
            const float bv = (role < 4) ? bias[n] : 0.f;
            #pragma unroll
            for (int reg = 0; reg < 4; reg++) {
                float v = acc[t][reg] + bv;
                if (role < 2)      v = fast_sigmoid(v);
                else if (role < 4) v = fast_tanh(v);
                obuf[(size_t)(row0 + reg) * DS + n] = v;
            }
        }
    }
}

// ---------------- K2: scan; block = (b, d-half), 10 waves; LDS-staged inputs ----------------
// The 45-us bottleneck was global-load latency: the 8-t register ring (~270 cyc of
// compute) cannot cover ~300-900 cyc L2/L3/HBM latency at 2.5 waves/SIMD. Fix: stage
// e/a/w per 40-t chunk in double-buffered LDS with issue-early/write-late (T14) --
// coalesced loads for chunk c+1 are issued before computing chunk c (~1500 cyc cover),
// ds_write + 1 barrier at chunk end. The scan ring now reads LDS (~120 cyc, covered).
// Cross-wave reduce of the 10 partial reads per 8-t tile unchanged; final reads
// written directly as bf16 (same rounding point k3 consumes -> numerics identical).
__global__ __launch_bounds__(640) void k2_scan(
    const float* __restrict__ w_buf, const float* __restrict__ e_buf,
    const float* __restrict__ a_buf, const float* __restrict__ Mv0,
    unsigned short* __restrict__ reads)
{
    const int bi   = blockIdx.x;          // 0..127
    const int b    = bi >> 1;
    const int dh   = bi & 1;
    const int tid  = threadIdx.x;
    const int wv   = tid >> 6;            // 0..9 = m-group (5 m each)
    const int L    = tid & 63;
    const int d    = dh * 64 + L;
    const int m0e  = wv * 5;
    const int base = b * Tn;

    __shared__ float se_s[2][CH][64];     // 20.5 KB
    __shared__ float sa_s[2][CH][64];     // 20.5 KB
    __shared__ float sw_s[2][CH * SM];    // 16 KB
    __shared__ float red[2][WVS][8][64];  // 41 KB   (total ~98 KB -> 1 block/CU)

    float Mv[5];
    #pragma unroll
    for (int m = 0; m < 5; m++) Mv[m] = Mv0[(size_t)(m0e + m) * DS + d];

    const int r0 = tid >> 6, c0 = tid & 63;   // staging coords (10 rows x 64 cols per pass)

    // ---- prologue: stage chunk 0 into buffer 0 ----
    {
        const size_t ebase = (size_t)base * DS + dh * 64 + c0;
        #pragma unroll
        for (int pp = 0; pp < 4; pp++) {
            const int row = pp * 10 + r0;
            se_s[0][row][c0] = e_buf[ebase + (size_t)row * DS];
            sa_s[0][row][c0] = a_buf[ebase + (size_t)row * DS];
        }
        const int wbase = base * SM;
        #pragma unroll
        for (int pp = 0; pp < 4; pp++) {
            const int j = tid + pp * 640;
            if (j < CH * SM) sw_s[0][j] = w_buf[wbase + j];
        }
    }
    __syncthreads();

    float se[4][2], sa[4][2], sw[4][2][5];
    int p = 0;

    // ring stage ST <- local t TL (and TL+1) of the CURRENT chunk's LDS buffer.
    // Guarded: TL >= CH would cross into the not-yet-staged next chunk; those stages
    // are never consumed (each chunk re-inits stages 0-3), so skipping is safe.
    #define LOADST(ST, TL)                                                     \
        { const int tl_ = (TL);                                                \
          if (tl_ < CH) {                                                      \
            _Pragma("unroll")                                                  \
            for (int q_ = 0; q_ < 2; q_++) {                                   \
                se[ST][q_] = se_s[p][tl_ + q_][L];                             \
                sa[ST][q_] = sa_s[p][tl_ + q_][L];                             \
                _Pragma("unroll")                                              \
                for (int m_ = 0; m_ < 5; m_++)                                 \
                    sw[ST][q_][m_] = sw_s[p][(tl_ + q_) * SM + m0e + m_];      \
            } } }

    for (int c = 0; c < NCH; c++) {
        // T14 issue-early: next chunk's coalesced global loads -> registers
        float st_e[4], st_a[4], st_w[4];
        if (c + 1 < NCH) {
            const int tcn = (c + 1) * CH;
            const size_t ebase = (size_t)(base + tcn) * DS + dh * 64 + c0;
            #pragma unroll
            for (int pp = 0; pp < 4; pp++) {
                const int row = pp * 10 + r0;
                st_e[pp] = e_buf[ebase + (size_t)row * DS];
                st_a[pp] = a_buf[ebase + (size_t)row * DS];
            }
            const int wbase = (base + tcn) * SM;
            #pragma unroll
            for (int pp = 0; pp < 4; pp++) {
                const int j = tid + pp * 640;
                if (j < CH * SM) st_w[pp] = w_buf[wbase + j];
            }
        }

        LOADST(0, 0) LOADST(1, 2) LOADST(2, 4) LOADST(3, 6)

        #pragma unroll 1
        for (int ti = 0; ti < 5; ti++) {
            const int tlb = ti * 8;              // local tile base within chunk
            const int gi  = c * 5 + ti;          // global tile index (parity for red)
            const int pr  = gi & 1;
            #pragma unroll
            for (int sub = 0; sub < 4; sub++) {
                #pragma unroll
                for (int q = 0; q < 2; q++) {
                    const float ev = se[sub][q], av = sa[sub][q];
                    float rd = 0.f;
                    #pragma unroll
                    for (int m = 0; m < 5; m++) {
                        const float wm = sw[sub][q][m];
                        rd = fmaf(wm, Mv[m], rd);                            // read uses OLD Mv
                        Mv[m] = fmaf(-wm, fmaf(ev, Mv[m], -av), Mv[m]);      // Mv*(1-w*e)+w*a
                    }
                    red[pr][wv][sub * 2 + q][L] = rd;
                }
                LOADST(sub, tlb + sub * 2 + 8)
            }
            __syncthreads();
            // cross-wave reduce: 512 outputs (8 t x 64 d). Safe w/o 2nd barrier: red[pr]
            // is re-written 2 tiles later, after the NEXT barrier.
            if (tid < 512) {
                const int tt = tid >> 6, dd = tid & 63;
                float s = red[pr][0][tt][dd];
                #pragma unroll
                for (int g = 1; g < WVS; g++) s += red[pr][g][tt][dd];
                reads[(size_t)(base + c * CH + tlb + tt) * DS + dh * 64 + dd] = f2bf(s);
            }
        }

        // write-late: commit next chunk into the other LDS buffer, then barrier
        if (c + 1 < NCH) {
            #pragma unroll
            for (int pp = 0; pp < 4; pp++) {
                const int row = pp * 10 + r0;
                se_s[p ^ 1][row][c0] = st_e[pp];
                sa_s[p ^ 1][row][c0] = st_a[pp];
            }
            #pragma unroll
            for (int pp = 0; pp < 4; pp++) {
                const int j = tid + pp * 640;
                if (j < CH * SM) sw_s[p ^ 1][j] = st_w[pp];
            }
            __syncthreads();
            p ^= 1;
        }
    }
    #undef LOADST
}

// ---------------- K3: 2-wave blocks (n-halves); f-GEMM + pred with LDS combine ----------------
__global__ __launch_bounds__(128, 2) void k3_gemm(
    const unsigned short* __restrict__ reads, const float* __restrict__ kp_buf,
    const unsigned int* __restrict__ Bf0U, const float* __restrict__ fB,
    const float* __restrict__ pW, const float* __restrict__ pB,
    const int* __restrict__ skill, float* __restrict__ out)
{
    const int tid = threadIdx.x;
    const int wv  = tid >> 6;          // n-half: 0 -> cols 0-63, 1 -> cols 64-127
    const int L   = tid & 63, L15 = L & 15, quad = L >> 4;
    const int tok0 = blockIdx.x * 16;
    const int tokA = tok0 + L15;
    const int row0 = tok0 + quad * 4;

    __shared__ float sm[2][16];

    // A-frags: final reads, already bf16 in frag element order
    bfrag Rf[4];
    #pragma unroll
    for (int ki = 0; ki < 4; ki++)
        Rf[ki] = *(const bfrag*)(reads + (size_t)tokA * DS + ki * 32 + quad * 8);

    const bfrag* Bf0 = (const bfrag*)Bf0U;
    const int g0 = wv * 4;

    f32x4 acc[4];
    #pragma unroll
    for (int t = 0; t < 4; t++) acc[t] = (f32x4){0.f,0.f,0.f,0.f};

    #pragma unroll
    for (int half = 0; half < 2; half++) {
        bfrag bh[2][4];
        #pragma unroll
        for (int tt = 0; tt < 2; tt++)
            #pragma unroll
            for (int ki = 0; ki < 4; ki++)
                bh[tt][ki] = Bf0[(size_t)((g0 + half * 2 + tt) * 4 + ki) * 64 + L];
        #pragma unroll
        for (int ki = 0; ki < 4; ki++)
            #pragma unroll
            for (int tt = 0; tt < 2; tt++)
                acc[half * 2 + tt] = __builtin_amdgcn_mfma_f32_16x16x32_bf16(
                    Rf[ki], bh[tt][ki], acc[half * 2 + tt], 0, 0, 0);
    }

    const int nb = wv * 64;
    float f[4][4];   // [reg][t]
    #pragma unroll
    for (int t = 0; t < 4; t++) {
        const int n = nb + t * 16 + L15;
        const float fb = fB[n];
        #pragma unroll
        for (int reg = 0; reg < 4; reg++)
            f[reg][t] = fast_tanh(acc[t][reg] + kp_buf[(size_t)(row0 + reg) * DS + n] + fb);
    }

    // pred partial: this wave's 64-dim contribution, reduced over the 16 lanes (L15)
    #pragma unroll
    for (int reg = 0; reg < 4; reg++) {
        const int tok = row0 + reg;
        const int t = tok % Tn;
        const bool act = (t < Tn - 1);
        float contrib = 0.f;
        if (act) {
            const int sn = skill[tok + 1];
            const int ix = (sn < NUMC) ? sn : (NUMC - 1);
            const float* pr = pW + (size_t)ix * DS + nb + L15;
            #pragma unroll
            for (int t4 = 0; t4 < 4; t4++)
                contrib = fmaf(f[reg][t4], pr[t4 * 16], contrib);
        }
        #pragma unroll
        for (int msk = 1; msk <= 8; msk <<= 1)
            contrib += __shfl_xor(contrib, msk);
        if (L15 == 0) sm[wv][quad * 4 + reg] = contrib;
    }
    __syncthreads();
    if (tid < 16) {
        const int tok = tok0 + tid;
        const int t = tok % Tn;
        if (t < Tn - 1) {
            const int sn = skill[tok + 1];
            const int ix = (sn < NUMC) ? sn : (NUMC - 1);
            const float val = sm[0][tid] + sm[1][tid] + pB[ix];
            out[(size_t)(tok / Tn) * (Tn - 1) + t] = (sn < NUMC) ? fast_sigmoid(val) : 0.f;
        }
    }
}

extern "C" void kernel_launch(void* const* d_in, const int* in_sizes, int n_in,
                              void* d_out, int out_size, void* d_ws, size_t ws_size,
                              hipStream_t stream)
{
    const int*   skill  = (const int*)  d_in[0];
    const int*   answer = (const int*)  d_in[1];
    const float* k_emb  = (const float*)d_in[2];
    const float* v_emb  = (const float*)d_in[3];
    const float* Mk     = (const float*)d_in[4];
    const float* Mv0    = (const float*)d_in[5];
    const float* f_W    = (const float*)d_in[6];
    const float* f_b    = (const float*)d_in[7];
    const float* p_W    = (const float*)d_in[8];
    const float* p_b    = (const float*)d_in[9];
    const float* e_W    = (const float*)d_in[10];
    const float* e_b    = (const float*)d_in[11];
    const float* a_W    = (const float*)d_in[12];
    const float* a_b    = (const float*)d_in[13];
    float* out = (float*)d_out;

    float* ws     = (float*)d_ws;
    float* w_buf  = ws;                                   // NTOK*SM
    float* e_buf  = w_buf  + (size_t)NTOK*SM;             // NTOK*DS
    float* a_buf  = e_buf  + (size_t)NTOK*DS;             // NTOK*DS
    float* kp_buf = a_buf  + (size_t)NTOK*DS;             // NTOK*DS
    unsigned short* reads = (unsigned short*)(kp_buf + (size_t)NTOK*DS);  // NTOK*DS bf16
    unsigned int* BeaU = (unsigned int*)(reads + (size_t)NTOK*DS);
    unsigned int* BkmU = BeaU + 4096 * 4;
    unsigned int* Bf0U = BkmU + 3072 * 4;

    k0_cast<<<36, 256, 0, stream>>>(e_W, a_W, f_W, Mk, BeaU, BkmU, Bf0U);
    k1_gemm<<<7*(NTOK/16), 64, 0, stream>>>(skill, answer, k_emb, v_emb,
        BeaU, BkmU, e_b, a_b, w_buf, e_buf, a_buf, kp_buf);
    k2_scan<<<Bsz*2, 640, 0, stream>>>(w_buf, e_buf, a_buf, Mv0, reads);
    k3_gemm<<<NTOK/16, 128, 0, stream>>>(reads, kp_buf, Bf0U, f_b,
        p_W, p_b, skill, out);
}